// Round 1
// baseline (5209.262 us; speedup 1.0000x reference)
//
#include <hip/hip_runtime.h>
#include <hip/hip_bf16.h>
#include <math.h>

// Problem constants
#define BB   2
#define TT   256
#define DD   256
#define HH   4
#define NN   32768
#define nn   8192
#define VV   32000
#define L_LAYERS 6
#define LN_EPS 1e-5f

// ---------------- block reduction helpers (256 threads = 4 waves) ----------------
__device__ __forceinline__ float block_sum(float v) {
    __shared__ float sh[4];
    #pragma unroll
    for (int o = 32; o > 0; o >>= 1) v += __shfl_down(v, o, 64);
    __syncthreads();
    if ((threadIdx.x & 63) == 0) sh[threadIdx.x >> 6] = v;
    __syncthreads();
    return sh[0] + sh[1] + sh[2] + sh[3];
}

__device__ __forceinline__ float block_max(float v) {
    __shared__ float sh[4];
    #pragma unroll
    for (int o = 32; o > 0; o >>= 1) v = fmaxf(v, __shfl_down(v, o, 64));
    __syncthreads();
    if ((threadIdx.x & 63) == 0) sh[threadIdx.x >> 6] = v;
    __syncthreads();
    return fmaxf(fmaxf(sh[0], sh[1]), fmaxf(sh[2], sh[3]));
}

// LayerNorm of one value per thread across a 256-wide row (no affine).
__device__ __forceinline__ float ln_val(float x) {
    float m = block_sum(x) * (1.0f / 256.0f);
    float d = x - m;
    float var = block_sum(d * d) * (1.0f / 256.0f);
    return d * rsqrtf(var + LN_EPS);
}

// ---------------- small row kernels ----------------
__global__ __launch_bounds__(256) void embed_ln_k(const int* __restrict__ idx,
                                                  const float* __restrict__ wte,
                                                  float* __restrict__ v) {
    int row = blockIdx.x;                  // b*T + t  (512 rows)
    int tok = idx[row];
    float x = wte[(size_t)tok * DD + threadIdx.x];
    v[(size_t)row * DD + threadIdx.x] = ln_val(x);
}

__global__ __launch_bounds__(256) void ln_rows_k(const float* __restrict__ in,
                                                 float* __restrict__ out) {
    size_t i = (size_t)blockIdx.x * DD + threadIdx.x;
    out[i] = ln_val(in[i]);
}

// v = ln(v + ln(yenc))
__global__ __launch_bounds__(256) void add_ln_ln_k(float* __restrict__ v,
                                                   const float* __restrict__ yenc) {
    size_t i = (size_t)blockIdx.x * DD + threadIdx.x;
    float t1 = ln_val(yenc[i]);
    float w = v[i] + t1;
    v[i] = ln_val(w);
}

// ---------------- RoPE: xr = rope(x), x is (B,H,T,n) ----------------
__global__ __launch_bounds__(256) void rope_k(const float* __restrict__ x,
                                              float* __restrict__ xr) {
    int gid = blockIdx.x * 256 + threadIdx.x;   // B*H*T*(n/2) = 8,388,608
    int p = gid & 4095;                          // pair index 0..4095
    int t = (gid >> 12) & 255;
    size_t base = ((size_t)(gid >> 12)) * nn + 2 * p;   // (bh*T+t)*n + 2p
    float2 xv = *(const float2*)(x + base);
    // inv_freq = 10000^(-p/4096); ln(10000) = 9.210340371976184
    float inv = __expf(-(float)p * (9.210340371976184f / 4096.0f));
    float ang = (float)t * inv;
    float s, c;
    sincosf(ang, &s, &c);
    float2 o;
    o.x = xv.x * c - xv.y * s;
    o.y = xv.y * c + xv.x * s;
    *(float2*)(xr + base) = o;
}

// ---------------- head GEMM: C = relu(A @ W_h) [optionally * x], A=(512,256) ----------------
// mode 0: C[(b*H+h)*T+t, col] layout (B,H,T,n), no multiply  (produces x)
// mode 1: C[(b*T+t), h*n+col]  layout (B,T,N), multiply by x (produces y_flat)
__global__ __launch_bounds__(256) void gemm_head_k(const float* __restrict__ A,
                                                   const float* __restrict__ W,
                                                   float* __restrict__ C,
                                                   const float* __restrict__ mulx,
                                                   int mode) {
    int h  = blockIdx.z;
    int m0 = blockIdx.y * 64;
    int n0 = blockIdx.x * 64;
    const float* Wh = W + (size_t)h * DD * nn;

    __shared__ float As[16][68];
    __shared__ float Bs[16][64];

    int tid = threadIdx.x;
    int tx = tid & 15, ty = tid >> 4;
    int ar = tid >> 2, ac = (tid & 3) * 4;
    int br = tid >> 4, bc = (tid & 15) * 4;

    float acc[4][4] = {};
    for (int k0 = 0; k0 < DD; k0 += 16) {
        float4 av = *(const float4*)(A + (size_t)(m0 + ar) * DD + k0 + ac);
        float4 bv = *(const float4*)(Wh + (size_t)(k0 + br) * nn + n0 + bc);
        As[ac + 0][ar] = av.x; As[ac + 1][ar] = av.y;
        As[ac + 2][ar] = av.z; As[ac + 3][ar] = av.w;
        *(float4*)&Bs[br][bc] = bv;
        __syncthreads();
        #pragma unroll
        for (int k = 0; k < 16; k++) {
            float4 a4 = *(const float4*)&As[k][ty * 4];
            float4 b4 = *(const float4*)&Bs[k][tx * 4];
            float aa[4] = {a4.x, a4.y, a4.z, a4.w};
            float bb[4] = {b4.x, b4.y, b4.z, b4.w};
            #pragma unroll
            for (int i = 0; i < 4; i++)
                #pragma unroll
                for (int j = 0; j < 4; j++)
                    acc[i][j] = fmaf(aa[i], bb[j], acc[i][j]);
        }
        __syncthreads();
    }

    #pragma unroll
    for (int i = 0; i < 4; i++) {
        int m = m0 + ty * 4 + i;
        int b = m >> 8, t = m & 255;
        #pragma unroll
        for (int j = 0; j < 4; j++) {
            int col = n0 + tx * 4 + j;
            float cv = fmaxf(acc[i][j], 0.0f);
            size_t bhtn = (((size_t)(b * HH + h)) * TT + t) * nn + col;
            if (mode == 0) {
                C[bhtn] = cv;
            } else {
                cv *= mulx[bhtn];
                C[((size_t)b * TT + t) * NN + (size_t)h * nn + col] = cv;
            }
        }
    }
}

// ---------------- scores: sc[z,t,s] = scale * dot(xr[z,t,:], xr[z,s,:]), K=8192 ----------------
__global__ __launch_bounds__(256) void scores_k(const float* __restrict__ xr,
                                                float* __restrict__ sc) {
    int z  = blockIdx.z;               // b*H + h, 0..7
    int s0 = blockIdx.x * 64;
    int t0 = blockIdx.y * 64;
    if (s0 > t0 + 63) return;          // fully-masked tile (causal)

    const float* Xz = xr + (size_t)z * TT * nn;
    __shared__ float As[16][68];
    __shared__ float Bs[16][68];

    int tid = threadIdx.x;
    int tx = tid & 15, ty = tid >> 4;
    int ar = tid >> 2, ac = (tid & 3) * 4;

    float acc[4][4] = {};
    for (int k0 = 0; k0 < nn; k0 += 16) {
        float4 av = *(const float4*)(Xz + (size_t)(t0 + ar) * nn + k0 + ac);
        float4 bv = *(const float4*)(Xz + (size_t)(s0 + ar) * nn + k0 + ac);
        As[ac + 0][ar] = av.x; As[ac + 1][ar] = av.y;
        As[ac + 2][ar] = av.z; As[ac + 3][ar] = av.w;
        Bs[ac + 0][ar] = bv.x; Bs[ac + 1][ar] = bv.y;
        Bs[ac + 2][ar] = bv.z; Bs[ac + 3][ar] = bv.w;
        __syncthreads();
        #pragma unroll
        for (int k = 0; k < 16; k++) {
            float4 a4 = *(const float4*)&As[k][ty * 4];
            float4 b4 = *(const float4*)&Bs[k][tx * 4];
            float aa[4] = {a4.x, a4.y, a4.z, a4.w};
            float bb[4] = {b4.x, b4.y, b4.z, b4.w};
            #pragma unroll
            for (int i = 0; i < 4; i++)
                #pragma unroll
                for (int j = 0; j < 4; j++)
                    acc[i][j] = fmaf(aa[i], bb[j], acc[i][j]);
        }
        __syncthreads();
    }

    const float scale = 0.011048543456039805f;   // 1/sqrt(8192)
    #pragma unroll
    for (int i = 0; i < 4; i++) {
        int t = t0 + ty * 4 + i;
        #pragma unroll
        for (int j = 0; j < 4; j++) {
            int s = s0 + tx * 4 + j;
            sc[(size_t)z * TT * TT + (size_t)t * TT + s] = acc[i][j] * scale;
        }
    }
}

// ---------------- causal softmax per (b,h,t) + mean over h -> am (B,T,T) ----------------
__global__ __launch_bounds__(256) void softmax_mean_k(const float* __restrict__ sc,
                                                      float* __restrict__ am) {
    int bt = blockIdx.x;
    int b = bt >> 8, t = bt & 255;
    int s = threadIdx.x;
    float acc = 0.0f;
    for (int h = 0; h < HH; h++) {
        const float* row = sc + (((size_t)(b * HH + h)) * TT + t) * TT;
        float val = (s <= t) ? row[s] : -1e30f;
        float mx = block_max(val);
        float e = (s <= t) ? expf(val - mx) : 0.0f;
        float sum = block_sum(e);
        acc += e / sum;
    }
    am[((size_t)b * TT + t) * TT + s] = acc * 0.25f;
}

// ---------------- generic NN GEMM with optional batching / split-K ----------------
// grid: (N/64, M/64, batch*kChunks). If kChunks>1, accumulate with atomicAdd (C pre-zeroed).
__global__ __launch_bounds__(256) void gemm_nn_k(const float* __restrict__ A,
                                                 const float* __restrict__ B,
                                                 float* __restrict__ C,
                                                 int M, int N, int K,
                                                 long lda, long ldb, long ldc,
                                                 long sAz, long sBz, long sCz,
                                                 int kChunks) {
    int z = blockIdx.z;
    int batch = z / kChunks;
    int kc = z % kChunks;
    int Keff = K / kChunks;
    A += (size_t)batch * sAz + (size_t)kc * Keff;
    B += (size_t)batch * sBz + (size_t)kc * Keff * ldb;
    C += (size_t)batch * sCz;

    int m0 = blockIdx.y * 64, n0 = blockIdx.x * 64;
    __shared__ float As[16][68];
    __shared__ float Bs[16][64];

    int tid = threadIdx.x;
    int tx = tid & 15, ty = tid >> 4;
    int ar = tid >> 2, ac = (tid & 3) * 4;
    int br = tid >> 4, bc = (tid & 15) * 4;

    float acc[4][4] = {};
    for (int k0 = 0; k0 < Keff; k0 += 16) {
        float4 av = *(const float4*)(A + (size_t)(m0 + ar) * lda + k0 + ac);
        float4 bv = *(const float4*)(B + (size_t)(k0 + br) * ldb + n0 + bc);
        As[ac + 0][ar] = av.x; As[ac + 1][ar] = av.y;
        As[ac + 2][ar] = av.z; As[ac + 3][ar] = av.w;
        *(float4*)&Bs[br][bc] = bv;
        __syncthreads();
        #pragma unroll
        for (int k = 0; k < 16; k++) {
            float4 a4 = *(const float4*)&As[k][ty * 4];
            float4 b4 = *(const float4*)&Bs[k][tx * 4];
            float aa[4] = {a4.x, a4.y, a4.z, a4.w};
            float bb[4] = {b4.x, b4.y, b4.z, b4.w};
            #pragma unroll
            for (int i = 0; i < 4; i++)
                #pragma unroll
                for (int j = 0; j < 4; j++)
                    acc[i][j] = fmaf(aa[i], bb[j], acc[i][j]);
        }
        __syncthreads();
    }

    #pragma unroll
    for (int i = 0; i < 4; i++) {
        int m = m0 + ty * 4 + i;
        #pragma unroll
        for (int j = 0; j < 4; j++) {
            int col = n0 + tx * 4 + j;
            size_t ci = (size_t)m * ldc + col;
            if (kChunks > 1) atomicAdd(&C[ci], acc[i][j]);
            else             C[ci] = acc[i][j];
        }
    }
}

// ---------------- launch ----------------
extern "C" void kernel_launch(void* const* d_in, const int* in_sizes, int n_in,
                              void* d_out, int out_size, void* d_ws, size_t ws_size,
                              hipStream_t stream) {
    const int*   idx  = (const int*)d_in[0];
    const float* wte  = (const float*)d_in[1];
    const float* enc  = (const float*)d_in[2];
    const float* Wx   = (const float*)d_in[3];
    const float* Wy   = (const float*)d_in[4];
    const float* Wro  = (const float*)d_in[5];
    float* out = (float*)d_out;

    // workspace carve-up (floats). Total = 34,734,080 floats = ~132.5 MiB
    float* ws   = (float*)d_ws;
    float* v    = ws;                       // 131072   (B,T,D)
    float* x    = v    + 131072;            // 16777216 (B,H,T,n)
    float* xr   = x    + 16777216;          // 16777216 (B,H,T,n)  reused as y_flat
    float* sc   = xr   + 16777216;          // 524288   (B,H,T,T)
    float* am   = sc   + 524288;            // 131072   (B,T,T)
    float* a    = am   + 131072;            // 131072   (B,T,D)
    float* lnA  = a    + 131072;            // 131072   (B,T,D)
    float* yenc = lnA  + 131072;            // 131072   (B,T,D)

    // v = ln(wte[idx])
    embed_ln_k<<<BB * TT, 256, 0, stream>>>(idx, wte, v);

    for (int l = 0; l < L_LAYERS; l++) {
        // x = relu(v @ Wx[h])  -> (B,H,T,n)
        gemm_head_k<<<dim3(nn / 64, (BB * TT) / 64, HH), 256, 0, stream>>>(v, Wx, x, nullptr, 0);

        // xr = rope(x)
        rope_k<<<(BB * HH * TT * (nn / 2)) / 256, 256, 0, stream>>>(x, xr);

        // sc = scale * xr @ xr^T  per (b,h)
        scores_k<<<dim3(TT / 64, TT / 64, BB * HH), 256, 0, stream>>>(xr, sc);

        // softmax (causal) + mean over heads
        softmax_mean_k<<<BB * TT, 256, 0, stream>>>(sc, am);

        // a = am @ v (per b)
        gemm_nn_k<<<dim3(DD / 64, TT / 64, BB), 256, 0, stream>>>(
            am, v, a, TT, DD, TT,
            (long)TT, (long)DD, (long)DD,
            (long)TT * TT, (long)TT * DD, (long)TT * DD, 1);

        // lnA = ln(a)
        ln_rows_k<<<BB * TT, 256, 0, stream>>>(a, lnA);

        // y_flat = relu(lnA @ Wy[h]) * x  -> (B,T,N) into xr buffer
        gemm_head_k<<<dim3(nn / 64, (BB * TT) / 64, HH), 256, 0, stream>>>(lnA, Wy, xr, x, 1);

        // yenc = y_flat @ enc  (split-K 16, atomic accumulate)
        hipMemsetAsync(yenc, 0, (size_t)131072 * sizeof(float), stream);
        gemm_nn_k<<<dim3(DD / 64, (BB * TT) / 64, 16), 256, 0, stream>>>(
            xr, enc, yenc, BB * TT, DD, NN,
            (long)NN, (long)DD, (long)DD,
            0L, 0L, 0L, 16);

        // v = ln(v + ln(yenc))
        add_ln_ln_k<<<BB * TT, 256, 0, stream>>>(v, yenc);
    }

    // out = v @ readout  (512 x 32000, K=256)
    gemm_nn_k<<<dim3(VV / 64, (BB * TT) / 64, 1), 256, 0, stream>>>(
        v, Wro, out, BB * TT, VV, DD,
        (long)DD, (long)VV, (long)VV,
        0L, 0L, 0L, 1);
}

// Round 2
// 3105.985 us; speedup vs baseline: 1.6772x; 1.6772x over previous
//
#include <hip/hip_runtime.h>
#include <hip/hip_bf16.h>
#include <math.h>

// Problem constants
#define BB   2
#define TT   256
#define DD   256
#define HH   4
#define NN   32768
#define nn   8192
#define VV   32000
#define L_LAYERS 6
#define LN_EPS 1e-5f

typedef __attribute__((ext_vector_type(8))) short bf16x8;
typedef __attribute__((ext_vector_type(4))) float f32x4;

__device__ __forceinline__ unsigned short f2bf(float f) {
    union { float f; unsigned int u; } v; v.f = f;
    unsigned int r = (v.u + 0x7FFFu + ((v.u >> 16) & 1u)) >> 16;
    return (unsigned short)r;
}

// ---------------- block reduction helpers (256 threads = 4 waves) ----------------
__device__ __forceinline__ float block_sum(float v) {
    __shared__ float sh[4];
    #pragma unroll
    for (int o = 32; o > 0; o >>= 1) v += __shfl_down(v, o, 64);
    __syncthreads();
    if ((threadIdx.x & 63) == 0) sh[threadIdx.x >> 6] = v;
    __syncthreads();
    return sh[0] + sh[1] + sh[2] + sh[3];
}

__device__ __forceinline__ float block_max(float v) {
    __shared__ float sh[4];
    #pragma unroll
    for (int o = 32; o > 0; o >>= 1) v = fmaxf(v, __shfl_down(v, o, 64));
    __syncthreads();
    if ((threadIdx.x & 63) == 0) sh[threadIdx.x >> 6] = v;
    __syncthreads();
    return fmaxf(fmaxf(sh[0], sh[1]), fmaxf(sh[2], sh[3]));
}

__device__ __forceinline__ float ln_val(float x) {
    float m = block_sum(x) * (1.0f / 256.0f);
    float d = x - m;
    float var = block_sum(d * d) * (1.0f / 256.0f);
    return d * rsqrtf(var + LN_EPS);
}

// ---------------- small row kernels ----------------
__global__ __launch_bounds__(256) void embed_ln_k(const int* __restrict__ idx,
                                                  const float* __restrict__ wte,
                                                  float* __restrict__ v) {
    int row = blockIdx.x;
    int tok = idx[row];
    float x = wte[(size_t)tok * DD + threadIdx.x];
    v[(size_t)row * DD + threadIdx.x] = ln_val(x);
}

__global__ __launch_bounds__(256) void ln_rows_k(const float* __restrict__ in,
                                                 float* __restrict__ out) {
    size_t i = (size_t)blockIdx.x * DD + threadIdx.x;
    out[i] = ln_val(in[i]);
}

__global__ __launch_bounds__(256) void add_ln_ln_k(float* __restrict__ v,
                                                   const float* __restrict__ yenc) {
    size_t i = (size_t)blockIdx.x * DD + threadIdx.x;
    float t1 = ln_val(yenc[i]);
    float w = v[i] + t1;
    v[i] = ln_val(w);
}

// ---------------- RoPE ----------------
__global__ __launch_bounds__(256) void rope_k(const float* __restrict__ x,
                                              float* __restrict__ xr) {
    int gid = blockIdx.x * 256 + threadIdx.x;
    int p = gid & 4095;
    int t = (gid >> 12) & 255;
    size_t base = ((size_t)(gid >> 12)) * nn + 2 * p;
    float2 xv = *(const float2*)(x + base);
    float inv = __expf(-(float)p * (9.210340371976184f / 4096.0f));
    float ang = (float)t * inv;
    float s, c;
    sincosf(ang, &s, &c);
    float2 o;
    o.x = xv.x * c - xv.y * s;
    o.y = xv.y * c + xv.x * s;
    *(float2*)(xr + base) = o;
}

// ---------------- head GEMM: C = relu(A @ W_h), optionally *x and bf16 output ----------------
// mode 0: C fp32, layout (B,H,T,n)
// mode 1: Cb bf16, layout (B,T,N), multiplied by mulx (B,H,T,n)
__global__ __launch_bounds__(256) void gemm_head_k(const float* __restrict__ A,
                                                   const float* __restrict__ W,
                                                   float* __restrict__ C,
                                                   unsigned short* __restrict__ Cb,
                                                   const float* __restrict__ mulx,
                                                   int mode) {
    int h  = blockIdx.z;
    int m0 = blockIdx.y * 64;
    int n0 = blockIdx.x * 64;
    const float* Wh = W + (size_t)h * DD * nn;

    __shared__ float As[16][68];
    __shared__ float Bs[16][64];

    int tid = threadIdx.x;
    int tx = tid & 15, ty = tid >> 4;
    int ar = tid >> 2, ac = (tid & 3) * 4;
    int br = tid >> 4, bc = (tid & 15) * 4;

    float acc[4][4] = {};
    for (int k0 = 0; k0 < DD; k0 += 16) {
        float4 av = *(const float4*)(A + (size_t)(m0 + ar) * DD + k0 + ac);
        float4 bv = *(const float4*)(Wh + (size_t)(k0 + br) * nn + n0 + bc);
        As[ac + 0][ar] = av.x; As[ac + 1][ar] = av.y;
        As[ac + 2][ar] = av.z; As[ac + 3][ar] = av.w;
        *(float4*)&Bs[br][bc] = bv;
        __syncthreads();
        #pragma unroll
        for (int k = 0; k < 16; k++) {
            float4 a4 = *(const float4*)&As[k][ty * 4];
            float4 b4 = *(const float4*)&Bs[k][tx * 4];
            float aa[4] = {a4.x, a4.y, a4.z, a4.w};
            float bb[4] = {b4.x, b4.y, b4.z, b4.w};
            #pragma unroll
            for (int i = 0; i < 4; i++)
                #pragma unroll
                for (int j = 0; j < 4; j++)
                    acc[i][j] = fmaf(aa[i], bb[j], acc[i][j]);
        }
        __syncthreads();
    }

    #pragma unroll
    for (int i = 0; i < 4; i++) {
        int m = m0 + ty * 4 + i;
        int b = m >> 8, t = m & 255;
        #pragma unroll
        for (int j = 0; j < 4; j++) {
            int col = n0 + tx * 4 + j;
            float cv = fmaxf(acc[i][j], 0.0f);
            size_t bhtn = (((size_t)(b * HH + h)) * TT + t) * nn + col;
            if (mode == 0) {
                C[bhtn] = cv;
            } else {
                cv *= mulx[bhtn];
                Cb[((size_t)b * TT + t) * NN + (size_t)h * nn + col] = f2bf(cv);
            }
        }
    }
}

// ---------------- scores with split-K: sc += scale * partial dot over 512-wide K chunk ----------
// grid: (4, 4, 8*SCHUNKS). sc pre-zeroed, atomicAdd accumulate.
#define SCHUNKS 16
__global__ __launch_bounds__(256) void scores_k(const float* __restrict__ xr,
                                                float* __restrict__ sc) {
    int z  = blockIdx.z;
    int zh = z / SCHUNKS;              // b*H + h
    int kc = z % SCHUNKS;
    int s0 = blockIdx.x * 64;
    int t0 = blockIdx.y * 64;
    if (s0 > t0 + 63) return;          // fully-masked tile (causal)

    const int Keff = nn / SCHUNKS;     // 512
    const float* Xz = xr + (size_t)zh * TT * nn + (size_t)kc * Keff;
    __shared__ float As[16][68];
    __shared__ float Bs[16][68];

    int tid = threadIdx.x;
    int tx = tid & 15, ty = tid >> 4;
    int ar = tid >> 2, ac = (tid & 3) * 4;

    float acc[4][4] = {};
    for (int k0 = 0; k0 < Keff; k0 += 16) {
        float4 av = *(const float4*)(Xz + (size_t)(t0 + ar) * nn + k0 + ac);
        float4 bv = *(const float4*)(Xz + (size_t)(s0 + ar) * nn + k0 + ac);
        As[ac + 0][ar] = av.x; As[ac + 1][ar] = av.y;
        As[ac + 2][ar] = av.z; As[ac + 3][ar] = av.w;
        Bs[ac + 0][ar] = bv.x; Bs[ac + 1][ar] = bv.y;
        Bs[ac + 2][ar] = bv.z; Bs[ac + 3][ar] = bv.w;
        __syncthreads();
        #pragma unroll
        for (int k = 0; k < 16; k++) {
            float4 a4 = *(const float4*)&As[k][ty * 4];
            float4 b4 = *(const float4*)&Bs[k][tx * 4];
            float aa[4] = {a4.x, a4.y, a4.z, a4.w};
            float bb[4] = {b4.x, b4.y, b4.z, b4.w};
            #pragma unroll
            for (int i = 0; i < 4; i++)
                #pragma unroll
                for (int j = 0; j < 4; j++)
                    acc[i][j] = fmaf(aa[i], bb[j], acc[i][j]);
        }
        __syncthreads();
    }

    const float scale = 0.011048543456039805f;   // 1/sqrt(8192)
    #pragma unroll
    for (int i = 0; i < 4; i++) {
        int t = t0 + ty * 4 + i;
        #pragma unroll
        for (int j = 0; j < 4; j++) {
            int s = s0 + tx * 4 + j;
            atomicAdd(&sc[(size_t)zh * TT * TT + (size_t)t * TT + s], acc[i][j] * scale);
        }
    }
}

// ---------------- causal softmax per (b,h,t) + mean over h -> am (B,T,T) ----------------
__global__ __launch_bounds__(256) void softmax_mean_k(const float* __restrict__ sc,
                                                      float* __restrict__ am) {
    int bt = blockIdx.x;
    int b = bt >> 8, t = bt & 255;
    int s = threadIdx.x;
    float acc = 0.0f;
    for (int h = 0; h < HH; h++) {
        const float* row = sc + (((size_t)(b * HH + h)) * TT + t) * TT;
        float val = (s <= t) ? row[s] : -1e30f;
        float mx = block_max(val);
        float e = (s <= t) ? expf(val - mx) : 0.0f;
        float sum = block_sum(e);
        acc += e / sum;
    }
    am[((size_t)b * TT + t) * TT + s] = acc * 0.25f;
}

// ---------------- generic NN GEMM (fp32) ----------------
__global__ __launch_bounds__(256) void gemm_nn_k(const float* __restrict__ A,
                                                 const float* __restrict__ B,
                                                 float* __restrict__ C,
                                                 int M, int N, int K,
                                                 long lda, long ldb, long ldc,
                                                 long sAz, long sBz, long sCz) {
    int batch = blockIdx.z;
    A += (size_t)batch * sAz;
    B += (size_t)batch * sBz;
    C += (size_t)batch * sCz;

    int m0 = blockIdx.y * 64, n0 = blockIdx.x * 64;
    __shared__ float As[16][68];
    __shared__ float Bs[16][64];

    int tid = threadIdx.x;
    int tx = tid & 15, ty = tid >> 4;
    int ar = tid >> 2, ac = (tid & 3) * 4;
    int br = tid >> 4, bc = (tid & 15) * 4;

    float acc[4][4] = {};
    for (int k0 = 0; k0 < K; k0 += 16) {
        float4 av = *(const float4*)(A + (size_t)(m0 + ar) * lda + k0 + ac);
        float4 bv = *(const float4*)(B + (size_t)(k0 + br) * ldb + n0 + bc);
        As[ac + 0][ar] = av.x; As[ac + 1][ar] = av.y;
        As[ac + 2][ar] = av.z; As[ac + 3][ar] = av.w;
        *(float4*)&Bs[br][bc] = bv;
        __syncthreads();
        #pragma unroll
        for (int k = 0; k < 16; k++) {
            float4 a4 = *(const float4*)&As[k][ty * 4];
            float4 b4 = *(const float4*)&Bs[k][tx * 4];
            float aa[4] = {a4.x, a4.y, a4.z, a4.w};
            float bb[4] = {b4.x, b4.y, b4.z, b4.w};
            #pragma unroll
            for (int i = 0; i < 4; i++)
                #pragma unroll
                for (int j = 0; j < 4; j++)
                    acc[i][j] = fmaf(aa[i], bb[j], acc[i][j]);
        }
        __syncthreads();
    }

    #pragma unroll
    for (int i = 0; i < 4; i++) {
        int m = m0 + ty * 4 + i;
        #pragma unroll
        for (int j = 0; j < 4; j++) {
            int col = n0 + tx * 4 + j;
            C[(size_t)m * ldc + col] = acc[i][j];
        }
    }
}

// ---------------- enc (32768x256 f32, row-major) -> encT (256x32768 bf16) ----------------
__global__ __launch_bounds__(256) void enc_transpose_k(const float* __restrict__ enc,
                                                       unsigned short* __restrict__ encT) {
    __shared__ float tile[64][65];
    int k0 = blockIdx.x * 64;
    int n0 = blockIdx.y * 64;
    int c = threadIdx.x & 63;
    int r0 = threadIdx.x >> 6;
    #pragma unroll
    for (int i = 0; i < 16; i++) {
        int r = r0 + i * 4;
        tile[r][c] = enc[(size_t)(k0 + r) * DD + n0 + c];
    }
    __syncthreads();
    #pragma unroll
    for (int i = 0; i < 16; i++) {
        int r = r0 + i * 4;   // n-local
        encT[(size_t)(n0 + r) * NN + k0 + c] = f2bf(tile[c][r]);
    }
}

// ---------------- encoder GEMM via bf16 MFMA: yenc += ybf(512x32768) @ enc(32768x256) ----------
// grid (2 n-tiles, 4 m-tiles, 32 k-chunks of 1024). yenc pre-zeroed, atomicAdd.
__global__ __launch_bounds__(256) void gemm_enc_mfma(const unsigned short* __restrict__ A,
                                                     const unsigned short* __restrict__ Bt,
                                                     float* __restrict__ C) {
    int n0 = blockIdx.x * 128;
    int m0 = blockIdx.y * 128;
    int kbase = blockIdx.z * 1024;

    __shared__ unsigned short As[128][40];
    __shared__ unsigned short Bs[128][40];

    int tid = threadIdx.x;
    int lane = tid & 63;
    int w = tid >> 6;
    int rowoff = (w >> 1) * 64, coloff = (w & 1) * 64;
    int fr = lane & 15, fq = (lane >> 4) * 8;

    f32x4 acc[4][4] = {};

    for (int k0 = 0; k0 < 1024; k0 += 32) {
        #pragma unroll
        for (int i = 0; i < 2; i++) {
            int c = tid + i * 256;
            int r = c >> 2, ko = (c & 3) * 8;
            *(uint4*)&As[r][ko] = *(const uint4*)(A + (size_t)(m0 + r) * NN + kbase + k0 + ko);
            *(uint4*)&Bs[r][ko] = *(const uint4*)(Bt + (size_t)(n0 + r) * NN + kbase + k0 + ko);
        }
        __syncthreads();
        bf16x8 af[4], bfr[4];
        #pragma unroll
        for (int mi = 0; mi < 4; mi++) af[mi] = *(const bf16x8*)&As[rowoff + mi * 16 + fr][fq];
        #pragma unroll
        for (int ni = 0; ni < 4; ni++) bfr[ni] = *(const bf16x8*)&Bs[coloff + ni * 16 + fr][fq];
        #pragma unroll
        for (int mi = 0; mi < 4; mi++)
            #pragma unroll
            for (int ni = 0; ni < 4; ni++)
                acc[mi][ni] = __builtin_amdgcn_mfma_f32_16x16x32_bf16(af[mi], bfr[ni], acc[mi][ni], 0, 0, 0);
        __syncthreads();
    }

    int r4 = (lane >> 4) * 4, cc = lane & 15;
    #pragma unroll
    for (int mi = 0; mi < 4; mi++)
        #pragma unroll
        for (int ni = 0; ni < 4; ni++)
            #pragma unroll
            for (int r = 0; r < 4; r++) {
                int row = m0 + rowoff + mi * 16 + r4 + r;
                int col = n0 + coloff + ni * 16 + cc;
                atomicAdd(&C[(size_t)row * DD + col], acc[mi][ni][r]);
            }
}

// ---------------- launch ----------------
extern "C" void kernel_launch(void* const* d_in, const int* in_sizes, int n_in,
                              void* d_out, int out_size, void* d_ws, size_t ws_size,
                              hipStream_t stream) {
    const int*   idx  = (const int*)d_in[0];
    const float* wte  = (const float*)d_in[1];
    const float* enc  = (const float*)d_in[2];
    const float* Wx   = (const float*)d_in[3];
    const float* Wy   = (const float*)d_in[4];
    const float* Wro  = (const float*)d_in[5];
    float* out = (float*)d_out;

    // workspace carve-up (floats). Total = 34,734,080 floats = ~132.5 MiB
    float* ws   = (float*)d_ws;
    float* v    = ws;                       // 131072   (B,T,D)
    float* x    = v    + 131072;            // 16777216 (B,H,T,n); late-layer reuse: encT bf16
    float* xr   = x    + 16777216;          // 16777216 (B,H,T,n); late-layer reuse: ybf bf16
    float* sc   = xr   + 16777216;          // 524288   (B,H,T,T)
    float* am   = sc   + 524288;            // 131072   (B,T,T)
    float* a    = am   + 131072;            // 131072   (B,T,D)
    float* lnA  = a    + 131072;            // 131072   (B,T,D)
    float* yenc = lnA  + 131072;            // 131072   (B,T,D)
    unsigned short* encT = (unsigned short*)x;   // 256x32768 bf16 (x is dead by then)
    unsigned short* ybf  = (unsigned short*)xr;  // 512x32768 bf16 (xr dead after scores)

    // v = ln(wte[idx])
    embed_ln_k<<<BB * TT, 256, 0, stream>>>(idx, wte, v);

    for (int l = 0; l < L_LAYERS; l++) {
        // x = relu(v @ Wx[h])  -> (B,H,T,n) fp32
        gemm_head_k<<<dim3(nn / 64, (BB * TT) / 64, HH), 256, 0, stream>>>(v, Wx, x, nullptr, nullptr, 0);

        // xr = rope(x)
        rope_k<<<(BB * HH * TT * (nn / 2)) / 256, 256, 0, stream>>>(x, xr);

        // sc = scale * xr @ xr^T  per (b,h), split-K 16, atomic accumulate
        hipMemsetAsync(sc, 0, (size_t)524288 * sizeof(float), stream);
        scores_k<<<dim3(TT / 64, TT / 64, BB * HH * SCHUNKS), 256, 0, stream>>>(xr, sc);

        // softmax (causal) + mean over heads
        softmax_mean_k<<<BB * TT, 256, 0, stream>>>(sc, am);

        // a = am @ v (per b)
        gemm_nn_k<<<dim3(DD / 64, TT / 64, BB), 256, 0, stream>>>(
            am, v, a, TT, DD, TT,
            (long)TT, (long)DD, (long)DD,
            (long)TT * TT, (long)TT * DD, (long)TT * DD);

        // lnA = ln(a)
        ln_rows_k<<<BB * TT, 256, 0, stream>>>(a, lnA);

        // ybf = bf16( relu(lnA @ Wy[h]) * x )  -> (B,T,N) bf16 into xr region
        gemm_head_k<<<dim3(nn / 64, (BB * TT) / 64, HH), 256, 0, stream>>>(lnA, Wy, nullptr, ybf, x, 1);

        // encT = transpose+bf16(enc) into x region (x dead now)
        enc_transpose_k<<<dim3(NN / 64, DD / 64), 256, 0, stream>>>(enc, encT);

        // yenc = ybf @ enc  via MFMA, split-K 32, atomic accumulate
        hipMemsetAsync(yenc, 0, (size_t)131072 * sizeof(float), stream);
        gemm_enc_mfma<<<dim3(2, 4, 32), 256, 0, stream>>>(ybf, encT, yenc);

        // v = ln(v + ln(yenc))
        add_ln_ln_k<<<BB * TT, 256, 0, stream>>>(v, yenc);
    }

    // out = v @ readout  (512 x 32000, K=256)
    gemm_nn_k<<<dim3(VV / 64, (BB * TT) / 64, 1), 256, 0, stream>>>(
        v, Wro, out, BB * TT, VV, DD,
        (long)DD, (long)VV, (long)VV,
        0L, 0L, 0L);
}

// Round 3
// 1847.277 us; speedup vs baseline: 2.8200x; 1.6814x over previous
//
#include <hip/hip_runtime.h>
#include <hip/hip_bf16.h>
#include <math.h>

// Problem constants
#define BB   2
#define TT   256
#define DD   256
#define HH   4
#define NN   32768
#define nn   8192
#define VV   32000
#define L_LAYERS 6
#define LN_EPS 1e-5f

typedef __attribute__((ext_vector_type(8))) short bf16x8;
typedef __attribute__((ext_vector_type(4))) float f32x4;

__device__ __forceinline__ unsigned short f2bf(float f) {
    union { float f; unsigned int u; } v; v.f = f;
    unsigned int r = (v.u + 0x7FFFu + ((v.u >> 16) & 1u)) >> 16;
    return (unsigned short)r;
}
__device__ __forceinline__ float bf2f(unsigned short h) {
    union { unsigned int u; float f; } v; v.u = ((unsigned int)h) << 16;
    return v.f;
}
// split x into hi+lo bf16 (hi+lo reproduces x to ~2^-17 rel)
__device__ __forceinline__ void split_hl(float x, unsigned short& h, unsigned short& l) {
    h = f2bf(x);
    l = f2bf(x - bf2f(h));
}
// load a bf16x8 fragment from LDS with 8B-granular reads (rows padded to 36 shorts)
__device__ __forceinline__ bf16x8 ld_frag(const unsigned short* p) {
    union { bf16x8 v; uint2 u[2]; } r;
    r.u[0] = *(const uint2*)(p);
    r.u[1] = *(const uint2*)(p + 4);
    return r.v;
}

// ---------------- block reduction helpers (256 threads = 4 waves) ----------------
__device__ __forceinline__ float block_sum(float v) {
    __shared__ float sh[4];
    #pragma unroll
    for (int o = 32; o > 0; o >>= 1) v += __shfl_down(v, o, 64);
    __syncthreads();
    if ((threadIdx.x & 63) == 0) sh[threadIdx.x >> 6] = v;
    __syncthreads();
    return sh[0] + sh[1] + sh[2] + sh[3];
}
__device__ __forceinline__ float block_max(float v) {
    __shared__ float sh[4];
    #pragma unroll
    for (int o = 32; o > 0; o >>= 1) v = fmaxf(v, __shfl_down(v, o, 64));
    __syncthreads();
    if ((threadIdx.x & 63) == 0) sh[threadIdx.x >> 6] = v;
    __syncthreads();
    return fmaxf(fmaxf(sh[0], sh[1]), fmaxf(sh[2], sh[3]));
}
__device__ __forceinline__ float ln_val(float x) {
    float m = block_sum(x) * (1.0f / 256.0f);
    float d = x - m;
    float var = block_sum(d * d) * (1.0f / 256.0f);
    return d * rsqrtf(var + LN_EPS);
}

// ---------------- small row kernels (also emit hi/lo bf16 of output) ----------------
__global__ __launch_bounds__(256) void embed_ln_k(const int* __restrict__ idx,
                                                  const float* __restrict__ wte,
                                                  float* __restrict__ v,
                                                  unsigned short* __restrict__ vh,
                                                  unsigned short* __restrict__ vl) {
    int row = blockIdx.x;
    int tok = idx[row];
    float x = wte[(size_t)tok * DD + threadIdx.x];
    float o = ln_val(x);
    size_t i = (size_t)row * DD + threadIdx.x;
    v[i] = o;
    unsigned short h, l; split_hl(o, h, l);
    vh[i] = h; vl[i] = l;
}

__global__ __launch_bounds__(256) void ln_rows_k(const float* __restrict__ in,
                                                 unsigned short* __restrict__ oh,
                                                 unsigned short* __restrict__ ol) {
    size_t i = (size_t)blockIdx.x * DD + threadIdx.x;
    float o = ln_val(in[i]);
    unsigned short h, l; split_hl(o, h, l);
    oh[i] = h; ol[i] = l;
}

__global__ __launch_bounds__(256) void add_ln_ln_k(float* __restrict__ v,
                                                   const float* __restrict__ yenc,
                                                   unsigned short* __restrict__ vh,
                                                   unsigned short* __restrict__ vl) {
    size_t i = (size_t)blockIdx.x * DD + threadIdx.x;
    float t1 = ln_val(yenc[i]);
    float w = v[i] + t1;
    float o = ln_val(w);
    v[i] = o;
    unsigned short h, l; split_hl(o, h, l);
    vh[i] = h; vl[i] = l;
}

// ---------------- unified compensated-bf16 MFMA GEMM, K=256, 128x128 tiles -------------
// A = Ahi/Alo (M x 256 bf16, row-major). W = fp32 [256][ldw] (+ h*wstride).
// mode 0: x-GEMM  -> Cf fp32 (B,H,T,n) layout, relu
// mode 1: y-GEMM  -> Cb bf16 (B,T,N)  layout, relu * mulx[(b,h,t,n)]
// mode 2: readout -> Cf fp32 [m*ldw + col]
__global__ __launch_bounds__(256) void gemm_cmp_k(const unsigned short* __restrict__ Ahi,
                                                  const unsigned short* __restrict__ Alo,
                                                  const float* __restrict__ W,
                                                  int ldw, long wstride,
                                                  float* __restrict__ Cf,
                                                  unsigned short* __restrict__ Cb,
                                                  const float* __restrict__ mulx,
                                                  int mode) {
    int h  = blockIdx.z;
    int n0 = blockIdx.x * 128;
    int m0 = blockIdx.y * 128;
    const float* Wh = W + (size_t)h * wstride;

    __shared__ unsigned short Ah[128][36], Al[128][36], Bh[128][36], Bl[128][36];

    int tid = threadIdx.x, lane = tid & 63, w = tid >> 6;
    int rowoff = (w >> 1) * 64, coloff = (w & 1) * 64;
    int fr = lane & 15, fq = (lane >> 4) * 8;
    int ra = tid >> 1, ha = tid & 1;      // A staging: row, k-half
    int cbn = tid & 127, rb0 = tid >> 7;  // B staging: col, row-base

    f32x4 acc[4][4] = {};

    for (int k0 = 0; k0 < 256; k0 += 32) {
        // global loads
        const unsigned short* pah = Ahi + (size_t)(m0 + ra) * 256 + k0 + ha * 16;
        const unsigned short* pal = Alo + (size_t)(m0 + ra) * 256 + k0 + ha * 16;
        uint4 gah0 = *(const uint4*)pah, gah1 = *(const uint4*)(pah + 8);
        uint4 gal0 = *(const uint4*)pal, gal1 = *(const uint4*)(pal + 8);
        float wv[16];
        #pragma unroll
        for (int i = 0; i < 16; i++)
            wv[i] = Wh[(size_t)(k0 + rb0 + 2 * i) * ldw + n0 + cbn];

        __syncthreads();
        { // A writes (16 shorts hi + 16 lo per thread)
            uint2* d0 = (uint2*)&Ah[ra][ha * 16];
            d0[0] = make_uint2(gah0.x, gah0.y); d0[1] = make_uint2(gah0.z, gah0.w);
            d0[2] = make_uint2(gah1.x, gah1.y); d0[3] = make_uint2(gah1.z, gah1.w);
            uint2* d1 = (uint2*)&Al[ra][ha * 16];
            d1[0] = make_uint2(gal0.x, gal0.y); d1[1] = make_uint2(gal0.z, gal0.w);
            d1[2] = make_uint2(gal1.x, gal1.y); d1[3] = make_uint2(gal1.z, gal1.w);
        }
        #pragma unroll
        for (int i = 0; i < 16; i++) {
            unsigned short hi, lo; split_hl(wv[i], hi, lo);
            Bh[cbn][rb0 + 2 * i] = hi;
            Bl[cbn][rb0 + 2 * i] = lo;
        }
        __syncthreads();

        bf16x8 afh[4], afl[4], bfh[4], bfl[4];
        #pragma unroll
        for (int mi = 0; mi < 4; mi++) {
            afh[mi] = ld_frag(&Ah[rowoff + mi * 16 + fr][fq]);
            afl[mi] = ld_frag(&Al[rowoff + mi * 16 + fr][fq]);
        }
        #pragma unroll
        for (int nj = 0; nj < 4; nj++) {
            bfh[nj] = ld_frag(&Bh[coloff + nj * 16 + fr][fq]);
            bfl[nj] = ld_frag(&Bl[coloff + nj * 16 + fr][fq]);
        }
        #pragma unroll
        for (int mi = 0; mi < 4; mi++)
            #pragma unroll
            for (int nj = 0; nj < 4; nj++) {
                acc[mi][nj] = __builtin_amdgcn_mfma_f32_16x16x32_bf16(afh[mi], bfh[nj], acc[mi][nj], 0, 0, 0);
                acc[mi][nj] = __builtin_amdgcn_mfma_f32_16x16x32_bf16(afh[mi], bfl[nj], acc[mi][nj], 0, 0, 0);
                acc[mi][nj] = __builtin_amdgcn_mfma_f32_16x16x32_bf16(afl[mi], bfh[nj], acc[mi][nj], 0, 0, 0);
            }
    }

    int r4 = (lane >> 4) * 4, cc = lane & 15;
    #pragma unroll
    for (int mi = 0; mi < 4; mi++)
        #pragma unroll
        for (int nj = 0; nj < 4; nj++)
            #pragma unroll
            for (int rr = 0; rr < 4; rr++) {
                int m   = m0 + rowoff + mi * 16 + r4 + rr;
                int col = n0 + coloff + nj * 16 + cc;
                float cv = acc[mi][nj][rr];
                if (mode == 0) {
                    cv = fmaxf(cv, 0.0f);
                    int b = m >> 8, t = m & 255;
                    Cf[(((size_t)(b * HH + h)) * TT + t) * (size_t)nn + col] = cv;
                } else if (mode == 1) {
                    cv = fmaxf(cv, 0.0f);
                    int b = m >> 8, t = m & 255;
                    size_t bhtn = (((size_t)(b * HH + h)) * TT + t) * (size_t)nn + col;
                    cv *= mulx[bhtn];
                    Cb[((size_t)(b * TT + t)) * NN + (size_t)h * nn + col] = f2bf(cv);
                } else {
                    Cf[(size_t)m * ldw + col] = cv;
                }
            }
}

// ---------------- scores: fused rope + compensated bf16 MFMA -----------------------------
// grid (3 causal tiles, 8 k-chunks of 1024, 8 zh). atomicAdd into pre-zeroed sc.
__global__ __launch_bounds__(256) void scores_mfma(const float* __restrict__ x,
                                                   float* __restrict__ sc) {
    int zh   = blockIdx.z;
    int kc   = blockIdx.y;
    int tile = blockIdx.x;               // 0:(0,0) 1:(128,0) 2:(128,128)
    int t0 = (tile >= 1) ? 128 : 0;
    int s0 = (tile == 2) ? 128 : 0;
    const float* Xz = x + (size_t)zh * TT * nn;

    __shared__ unsigned short Ah[128][36], Al[128][36], Bh[128][36], Bl[128][36];

    int tid = threadIdx.x, lane = tid & 63, w = tid >> 6;
    int rowoff = (w >> 1) * 64, coloff = (w & 1) * 64;
    int fr = lane & 15, fq = (lane >> 4) * 8;
    int ra = tid >> 1, ha = tid & 1;     // staging: row, k-half (16 elems)

    float rowT = (float)(t0 + ra);
    float rowS = (float)(s0 + ra);

    f32x4 acc[4][4] = {};

    for (int ks = 0; ks < 1024; ks += 32) {
        int kbase = kc * 1024 + ks;
        const float* pa = Xz + (size_t)(t0 + ra) * nn + kbase + ha * 16;
        const float* pb = Xz + (size_t)(s0 + ra) * nn + kbase + ha * 16;
        float4 a4[4], b4[4];
        #pragma unroll
        for (int q = 0; q < 4; q++) {
            a4[q] = *(const float4*)(pa + 4 * q);
            b4[q] = *(const float4*)(pb + 4 * q);
        }
        const float* af = (const float*)a4;
        const float* bf = (const float*)b4;

        unsigned short sah[16], sal[16], sbh[16], sbl[16];
        int pbase = (kbase >> 1) + ha * 8;
        #pragma unroll
        for (int j = 0; j < 8; j++) {
            float inv = __expf(-(float)(pbase + j) * (9.210340371976184f / 4096.0f));
            float angT = rowT * inv, angS = rowS * inv;
            float sT = __sinf(angT), cT = __cosf(angT);
            float sS = __sinf(angS), cS = __cosf(angS);
            float xe = af[2 * j], xo = af[2 * j + 1];
            float aoe = xe * cT - xo * sT;
            float aoo = xo * cT + xe * sT;
            xe = bf[2 * j]; xo = bf[2 * j + 1];
            float boe = xe * cS - xo * sS;
            float boo = xo * cS + xe * sS;
            split_hl(aoe, sah[2 * j], sal[2 * j]);
            split_hl(aoo, sah[2 * j + 1], sal[2 * j + 1]);
            split_hl(boe, sbh[2 * j], sbl[2 * j]);
            split_hl(boo, sbh[2 * j + 1], sbl[2 * j + 1]);
        }

        __syncthreads();
        {
            uint2* dah = (uint2*)&Ah[ra][ha * 16];
            uint2* dal = (uint2*)&Al[ra][ha * 16];
            uint2* dbh = (uint2*)&Bh[ra][ha * 16];
            uint2* dbl = (uint2*)&Bl[ra][ha * 16];
            const uint2* uah = (const uint2*)sah;
            const uint2* ual = (const uint2*)sal;
            const uint2* ubh = (const uint2*)sbh;
            const uint2* ubl = (const uint2*)sbl;
            #pragma unroll
            for (int q = 0; q < 4; q++) {
                dah[q] = uah[q]; dal[q] = ual[q];
                dbh[q] = ubh[q]; dbl[q] = ubl[q];
            }
        }
        __syncthreads();

        bf16x8 afh[4], afl[4], bfh[4], bfl[4];
        #pragma unroll
        for (int mi = 0; mi < 4; mi++) {
            afh[mi] = ld_frag(&Ah[rowoff + mi * 16 + fr][fq]);
            afl[mi] = ld_frag(&Al[rowoff + mi * 16 + fr][fq]);
        }
        #pragma unroll
        for (int nj = 0; nj < 4; nj++) {
            bfh[nj] = ld_frag(&Bh[coloff + nj * 16 + fr][fq]);
            bfl[nj] = ld_frag(&Bl[coloff + nj * 16 + fr][fq]);
        }
        #pragma unroll
        for (int mi = 0; mi < 4; mi++)
            #pragma unroll
            for (int nj = 0; nj < 4; nj++) {
                acc[mi][nj] = __builtin_amdgcn_mfma_f32_16x16x32_bf16(afh[mi], bfh[nj], acc[mi][nj], 0, 0, 0);
                acc[mi][nj] = __builtin_amdgcn_mfma_f32_16x16x32_bf16(afh[mi], bfl[nj], acc[mi][nj], 0, 0, 0);
                acc[mi][nj] = __builtin_amdgcn_mfma_f32_16x16x32_bf16(afl[mi], bfh[nj], acc[mi][nj], 0, 0, 0);
            }
    }

    const float scale = 0.011048543456039805f;   // 1/sqrt(8192)
    int r4 = (lane >> 4) * 4, cc = lane & 15;
    float* scz = sc + (size_t)zh * TT * TT;
    #pragma unroll
    for (int mi = 0; mi < 4; mi++)
        #pragma unroll
        for (int nj = 0; nj < 4; nj++)
            #pragma unroll
            for (int rr = 0; rr < 4; rr++) {
                int t = t0 + rowoff + mi * 16 + r4 + rr;
                int s = s0 + coloff + nj * 16 + cc;
                atomicAdd(&scz[(size_t)t * TT + s], acc[mi][nj][rr] * scale);
            }
}

// ---------------- causal softmax per (b,h,t) + mean over h -> am (B,T,T) ----------------
__global__ __launch_bounds__(256) void softmax_mean_k(const float* __restrict__ sc,
                                                      float* __restrict__ am) {
    int bt = blockIdx.x;
    int b = bt >> 8, t = bt & 255;
    int s = threadIdx.x;
    float acc = 0.0f;
    for (int h = 0; h < HH; h++) {
        const float* row = sc + (((size_t)(b * HH + h)) * TT + t) * TT;
        float val = (s <= t) ? row[s] : -1e30f;
        float mx = block_max(val);
        float e = (s <= t) ? expf(val - mx) : 0.0f;
        float sum = block_sum(e);
        acc += e / sum;
    }
    am[((size_t)b * TT + t) * TT + s] = acc * 0.25f;
}

// ---------------- generic NN GEMM (fp32) — used only for am @ v ----------------
__global__ __launch_bounds__(256) void gemm_nn_k(const float* __restrict__ A,
                                                 const float* __restrict__ B,
                                                 float* __restrict__ C,
                                                 int M, int N, int K,
                                                 long lda, long ldb, long ldc,
                                                 long sAz, long sBz, long sCz) {
    int batch = blockIdx.z;
    A += (size_t)batch * sAz;
    B += (size_t)batch * sBz;
    C += (size_t)batch * sCz;

    int m0 = blockIdx.y * 64, n0 = blockIdx.x * 64;
    __shared__ float As[16][68];
    __shared__ float Bs[16][64];

    int tid = threadIdx.x;
    int tx = tid & 15, ty = tid >> 4;
    int ar = tid >> 2, ac = (tid & 3) * 4;
    int br = tid >> 4, bc = (tid & 15) * 4;

    float acc[4][4] = {};
    for (int k0 = 0; k0 < K; k0 += 16) {
        float4 av = *(const float4*)(A + (size_t)(m0 + ar) * lda + k0 + ac);
        float4 bv = *(const float4*)(B + (size_t)(k0 + br) * ldb + n0 + bc);
        As[ac + 0][ar] = av.x; As[ac + 1][ar] = av.y;
        As[ac + 2][ar] = av.z; As[ac + 3][ar] = av.w;
        *(float4*)&Bs[br][bc] = bv;
        __syncthreads();
        #pragma unroll
        for (int k = 0; k < 16; k++) {
            float4 a4 = *(const float4*)&As[k][ty * 4];
            float4 b4 = *(const float4*)&Bs[k][tx * 4];
            float aa[4] = {a4.x, a4.y, a4.z, a4.w};
            float bb[4] = {b4.x, b4.y, b4.z, b4.w};
            #pragma unroll
            for (int i = 0; i < 4; i++)
                #pragma unroll
                for (int j = 0; j < 4; j++)
                    acc[i][j] = fmaf(aa[i], bb[j], acc[i][j]);
        }
        __syncthreads();
    }

    #pragma unroll
    for (int i = 0; i < 4; i++) {
        int m = m0 + ty * 4 + i;
        #pragma unroll
        for (int j = 0; j < 4; j++) {
            int col = n0 + tx * 4 + j;
            C[(size_t)m * ldc + col] = acc[i][j];
        }
    }
}

// ---------------- encoder GEMM: yenc += ybf(512x32768 bf16) @ enc(32768x256 fp32) --------
// plain bf16 (measured OK in R2). grid (2 n-tiles, 4 m-tiles, 32 k-chunks of 1024).
__global__ __launch_bounds__(256) void enc_mfma(const unsigned short* __restrict__ A,
                                                const float* __restrict__ enc,
                                                float* __restrict__ C) {
    int n0 = blockIdx.x * 128;
    int m0 = blockIdx.y * 128;
    int kbase = blockIdx.z * 1024;

    __shared__ unsigned short As[128][36], Bs[128][36];

    int tid = threadIdx.x, lane = tid & 63, w = tid >> 6;
    int rowoff = (w >> 1) * 64, coloff = (w & 1) * 64;
    int fr = lane & 15, fq = (lane >> 4) * 8;
    int ra = tid >> 1, ha = tid & 1;
    int cbn = tid & 127, rb0 = tid >> 7;

    f32x4 acc[4][4] = {};

    for (int k0 = 0; k0 < 1024; k0 += 32) {
        const unsigned short* pa = A + (size_t)(m0 + ra) * NN + kbase + k0 + ha * 16;
        uint4 ga0 = *(const uint4*)pa, ga1 = *(const uint4*)(pa + 8);
        float wv[16];
        #pragma unroll
        for (int i = 0; i < 16; i++)
            wv[i] = enc[(size_t)(kbase + k0 + rb0 + 2 * i) * DD + n0 + cbn];

        __syncthreads();
        {
            uint2* d = (uint2*)&As[ra][ha * 16];
            d[0] = make_uint2(ga0.x, ga0.y); d[1] = make_uint2(ga0.z, ga0.w);
            d[2] = make_uint2(ga1.x, ga1.y); d[3] = make_uint2(ga1.z, ga1.w);
        }
        #pragma unroll
        for (int i = 0; i < 16; i++)
            Bs[cbn][rb0 + 2 * i] = f2bf(wv[i]);
        __syncthreads();

        bf16x8 af[4], bfr[4];
        #pragma unroll
        for (int mi = 0; mi < 4; mi++) af[mi] = ld_frag(&As[rowoff + mi * 16 + fr][fq]);
        #pragma unroll
        for (int nj = 0; nj < 4; nj++) bfr[nj] = ld_frag(&Bs[coloff + nj * 16 + fr][fq]);
        #pragma unroll
        for (int mi = 0; mi < 4; mi++)
            #pragma unroll
            for (int nj = 0; nj < 4; nj++)
                acc[mi][nj] = __builtin_amdgcn_mfma_f32_16x16x32_bf16(af[mi], bfr[nj], acc[mi][nj], 0, 0, 0);
    }

    int r4 = (lane >> 4) * 4, cc = lane & 15;
    #pragma unroll
    for (int mi = 0; mi < 4; mi++)
        #pragma unroll
        for (int nj = 0; nj < 4; nj++)
            #pragma unroll
            for (int rr = 0; rr < 4; rr++) {
                int row = m0 + rowoff + mi * 16 + r4 + rr;
                int col = n0 + coloff + nj * 16 + cc;
                atomicAdd(&C[(size_t)row * DD + col], acc[mi][nj][rr]);
            }
}

// ---------------- launch ----------------
extern "C" void kernel_launch(void* const* d_in, const int* in_sizes, int n_in,
                              void* d_out, int out_size, void* d_ws, size_t ws_size,
                              hipStream_t stream) {
    const int*   idx  = (const int*)d_in[0];
    const float* wte  = (const float*)d_in[1];
    const float* enc  = (const float*)d_in[2];
    const float* Wx   = (const float*)d_in[3];
    const float* Wy   = (const float*)d_in[4];
    const float* Wro  = (const float*)d_in[5];
    float* out = (float*)d_out;

    // workspace carve-up (float units). Total 26,476,544 floats = ~101 MiB (< proven 132.5 MiB)
    float* ws   = (float*)d_ws;
    float* v    = ws;                        // 131072    (B,T,D) fp32
    float* x    = v    + 131072;             // 16777216  (B,H,T,n) fp32
    float* sc   = x    + 16777216;           // 524288    (B,H,T,T)
    float* am   = sc   + 524288;             // 131072    (B,T,T)
    float* a    = am   + 131072;             // 131072    (B,T,D)
    float* yenc = a    + 131072;             // 131072    (B,T,D)
    unsigned short* vh  = (unsigned short*)(yenc + 131072);   // 131072 shorts
    unsigned short* vl  = vh + 131072;
    unsigned short* lAh = vl + 131072;
    unsigned short* lAl = lAh + 131072;
    unsigned short* ybf = lAl + 131072;      // 16777216 shorts (B,T,N) bf16

    // v = ln(wte[idx]) (+ hi/lo)
    embed_ln_k<<<BB * TT, 256, 0, stream>>>(idx, wte, v, vh, vl);

    for (int l = 0; l < L_LAYERS; l++) {
        // x = relu(v @ Wx[h])  (compensated MFMA) -> fp32 (B,H,T,n)
        gemm_cmp_k<<<dim3(nn / 128, (BB * TT) / 128, HH), 256, 0, stream>>>(
            vh, vl, Wx, nn, (long)DD * nn, x, nullptr, nullptr, 0);

        // sc = scale * rope(x) @ rope(x)^T  (fused rope, compensated MFMA, split-K 8)
        hipMemsetAsync(sc, 0, (size_t)524288 * sizeof(float), stream);
        scores_mfma<<<dim3(3, 8, BB * HH), 256, 0, stream>>>(x, sc);

        // softmax (causal) + mean over heads
        softmax_mean_k<<<BB * TT, 256, 0, stream>>>(sc, am);

        // a = am @ v (per b), fp32
        gemm_nn_k<<<dim3(DD / 64, TT / 64, BB), 256, 0, stream>>>(
            am, v, a, TT, DD, TT,
            (long)TT, (long)DD, (long)DD,
            (long)TT * TT, (long)TT * DD, (long)TT * DD);

        // lnA = ln(a) -> hi/lo bf16
        ln_rows_k<<<BB * TT, 256, 0, stream>>>(a, lAh, lAl);

        // ybf = bf16( relu(lnA @ Wy[h]) * x )  (compensated MFMA) -> (B,T,N) bf16
        gemm_cmp_k<<<dim3(nn / 128, (BB * TT) / 128, HH), 256, 0, stream>>>(
            lAh, lAl, Wy, nn, (long)DD * nn, nullptr, ybf, x, 1);

        // yenc = ybf @ enc  (plain bf16 MFMA, split-K 32, atomic accumulate)
        hipMemsetAsync(yenc, 0, (size_t)131072 * sizeof(float), stream);
        enc_mfma<<<dim3(2, 4, 32), 256, 0, stream>>>(ybf, enc, yenc);

        // v = ln(v + ln(yenc)) (+ hi/lo)
        add_ln_ln_k<<<BB * TT, 256, 0, stream>>>(v, yenc, vh, vl);
    }

    // out = v @ readout  (compensated MFMA, 512 x 32000, K=256)
    gemm_cmp_k<<<dim3(VV / 128, (BB * TT) / 128, 1), 256, 0, stream>>>(
        vh, vl, Wro, VV, 0L, out, nullptr, nullptr, 2);
}

// Round 4
// 1245.801 us; speedup vs baseline: 4.1815x; 1.4828x over previous
//
#include <hip/hip_runtime.h>
#include <hip/hip_bf16.h>
#include <math.h>

// Problem constants
#define BB   2
#define TT   256
#define DD   256
#define HH   4
#define NN   32768
#define nn   8192
#define VV   32000
#define L_LAYERS 6
#define LN_EPS 1e-5f

typedef __attribute__((ext_vector_type(8))) short bf16x8;
typedef __attribute__((ext_vector_type(4))) float f32x4;

__device__ __forceinline__ unsigned short f2bf(float f) {
    union { float f; unsigned int u; } v; v.f = f;
    unsigned int r = (v.u + 0x7FFFu + ((v.u >> 16) & 1u)) >> 16;
    return (unsigned short)r;
}
__device__ __forceinline__ float bf2f(unsigned short h) {
    union { unsigned int u; float f; } v; v.u = ((unsigned int)h) << 16;
    return v.f;
}
__device__ __forceinline__ bf16x8 ld_frag(const unsigned short* p) {
    union { bf16x8 v; uint2 u[2]; } r;
    r.u[0] = *(const uint2*)(p);
    r.u[1] = *(const uint2*)(p + 4);
    return r.v;
}

// ---------------- block reduction helpers (256 threads = 4 waves) ----------------
__device__ __forceinline__ float block_sum(float v) {
    __shared__ float sh[4];
    #pragma unroll
    for (int o = 32; o > 0; o >>= 1) v += __shfl_down(v, o, 64);
    __syncthreads();
    if ((threadIdx.x & 63) == 0) sh[threadIdx.x >> 6] = v;
    __syncthreads();
    return sh[0] + sh[1] + sh[2] + sh[3];
}
__device__ __forceinline__ float block_max(float v) {
    __shared__ float sh[4];
    #pragma unroll
    for (int o = 32; o > 0; o >>= 1) v = fmaxf(v, __shfl_down(v, o, 64));
    __syncthreads();
    if ((threadIdx.x & 63) == 0) sh[threadIdx.x >> 6] = v;
    __syncthreads();
    return fmaxf(fmaxf(sh[0], sh[1]), fmaxf(sh[2], sh[3]));
}
__device__ __forceinline__ float ln_val(float x) {
    float m = block_sum(x) * (1.0f / 256.0f);
    float d = x - m;
    float var = block_sum(d * d) * (1.0f / 256.0f);
    return d * rsqrtf(var + LN_EPS);
}

// ---------------- small row kernels ----------------
__global__ __launch_bounds__(256) void embed_ln_k(const int* __restrict__ idx,
                                                  const float* __restrict__ wte,
                                                  float* __restrict__ v,
                                                  unsigned short* __restrict__ vb) {
    int row = blockIdx.x;
    int tok = idx[row];
    float x = wte[(size_t)tok * DD + threadIdx.x];
    float o = ln_val(x);
    size_t i = (size_t)row * DD + threadIdx.x;
    v[i] = o;
    vb[i] = f2bf(o);
}

__global__ __launch_bounds__(256) void ln_rows_k(const float* __restrict__ in,
                                                 unsigned short* __restrict__ ob) {
    size_t i = (size_t)blockIdx.x * DD + threadIdx.x;
    ob[i] = f2bf(ln_val(in[i]));
}

__global__ __launch_bounds__(256) void add_ln_ln_k(float* __restrict__ v,
                                                   const float* __restrict__ yenc,
                                                   unsigned short* __restrict__ vb) {
    size_t i = (size_t)blockIdx.x * DD + threadIdx.x;
    float t1 = ln_val(yenc[i]);
    float w = v[i] + t1;
    float o = ln_val(w);
    v[i] = o;
    vb[i] = f2bf(o);
}

// ---------------- transpose+convert: dst[c][r] bf16 = src[r][c] fp32 ----------------
__global__ __launch_bounds__(256) void tconv_k(const float* __restrict__ src,
                                               unsigned short* __restrict__ dst,
                                               int R, int C, long sstride, long dstride) {
    src += (size_t)blockIdx.z * sstride;
    dst += (size_t)blockIdx.z * dstride;
    __shared__ unsigned short tile[64][66];
    int c0 = blockIdx.x * 64, r0 = blockIdx.y * 64;
    int c = threadIdx.x & 63, q = threadIdx.x >> 6;
    #pragma unroll
    for (int i = 0; i < 16; i++) {
        int r = q + i * 4;
        tile[r][c] = f2bf(src[(size_t)(r0 + r) * C + c0 + c]);
    }
    __syncthreads();
    #pragma unroll
    for (int i = 0; i < 16; i++) {
        int r = q + i * 4;
        dst[(size_t)(c0 + r) * R + r0 + c] = tile[c][r];
    }
}

// ---------------- RoPE on bf16: xrb = rope(xb), (B,H,T,n) ----------------
__global__ __launch_bounds__(256) void rope_b_k(const unsigned short* __restrict__ xb,
                                                unsigned short* __restrict__ xrb) {
    int gid = blockIdx.x * 256 + threadIdx.x;    // B*H*T*n/8 = 2,097,152
    int grp = gid & 1023;                         // group of 8 shorts (4 pairs)
    int t = (gid >> 10) & 255;
    size_t base = (size_t)(gid >> 10) * nn + grp * 8;
    union { uint4 u; unsigned short s[8]; } xin, xout;
    xin.u = *(const uint4*)(xb + base);
    float tf = (float)t;
    #pragma unroll
    for (int j = 0; j < 4; j++) {
        int p = grp * 4 + j;
        float inv = __expf(-(float)p * (9.210340371976184f / 4096.0f));
        float ang = tf * inv;
        float s = __sinf(ang), c = __cosf(ang);
        float xe = bf2f(xin.s[2 * j]), xo = bf2f(xin.s[2 * j + 1]);
        xout.s[2 * j]     = f2bf(xe * c - xo * s);
        xout.s[2 * j + 1] = f2bf(xo * c + xe * s);
    }
    *(uint4*)(xrb + base) = xout.u;
}

// ---------------- shared BT-GEMM main loop: both operands bf16, k-contiguous ----------
// Block tile 128x128, 4 waves, each wave 64x64 via 4x4 16x16x32 MFMA frags (R2/R3-verified).
__device__ __forceinline__ void bt_mainloop(const unsigned short* Ap, long lda,
                                            const unsigned short* Bp, long ldb,
                                            int ksteps,
                                            unsigned short (*As)[36],
                                            unsigned short (*Bs)[36],
                                            f32x4 (&acc)[4][4]) {
    int tid = threadIdx.x;
    int ra = tid >> 1, pa = (tid & 1) * 16;
    int lane = tid & 63, w = tid >> 6;
    int rowoff = (w >> 1) * 64, coloff = (w & 1) * 64;
    int fr = lane & 15, fq = (lane >> 4) * 8;
    const unsigned short* ga = Ap + (size_t)ra * lda + pa;
    const unsigned short* gb = Bp + (size_t)ra * ldb + pa;
    uint4 a0 = *(const uint4*)ga, a1 = *(const uint4*)(ga + 8);
    uint4 b0 = *(const uint4*)gb, b1 = *(const uint4*)(gb + 8);
    for (int k = 0; k < ksteps; k++) {
        __syncthreads();
        uint2* da = (uint2*)&As[ra][pa];
        da[0] = make_uint2(a0.x, a0.y); da[1] = make_uint2(a0.z, a0.w);
        da[2] = make_uint2(a1.x, a1.y); da[3] = make_uint2(a1.z, a1.w);
        uint2* db = (uint2*)&Bs[ra][pa];
        db[0] = make_uint2(b0.x, b0.y); db[1] = make_uint2(b0.z, b0.w);
        db[2] = make_uint2(b1.x, b1.y); db[3] = make_uint2(b1.z, b1.w);
        if (k + 1 < ksteps) {
            ga += 32; gb += 32;
            a0 = *(const uint4*)ga; a1 = *(const uint4*)(ga + 8);
            b0 = *(const uint4*)gb; b1 = *(const uint4*)(gb + 8);
        }
        __syncthreads();
        bf16x8 af[4], bf[4];
        #pragma unroll
        for (int mi = 0; mi < 4; mi++) af[mi] = ld_frag(&As[rowoff + mi * 16 + fr][fq]);
        #pragma unroll
        for (int nj = 0; nj < 4; nj++) bf[nj] = ld_frag(&Bs[coloff + nj * 16 + fr][fq]);
        #pragma unroll
        for (int mi = 0; mi < 4; mi++)
            #pragma unroll
            for (int nj = 0; nj < 4; nj++)
                acc[mi][nj] = __builtin_amdgcn_mfma_f32_16x16x32_bf16(af[mi], bf[nj], acc[mi][nj], 0, 0, 0);
    }
}

// ---------------- head GEMM: relu(vb @ WxT[h]) -> xb (mode 0) / y path (mode 1) -------
__global__ __launch_bounds__(256) void gemm_head_bt(const unsigned short* __restrict__ A,
                                                    const unsigned short* __restrict__ Wt,
                                                    unsigned short* __restrict__ Cx,
                                                    const unsigned short* __restrict__ mulx,
                                                    unsigned short* __restrict__ Cy,
                                                    int mode) {
    int h = blockIdx.z;
    int n0 = blockIdx.x * 128, m0 = blockIdx.y * 128;
    __shared__ unsigned short As[128][36], Bs[128][36];
    f32x4 acc[4][4] = {};
    bt_mainloop(A + (size_t)m0 * DD, DD,
                Wt + (size_t)h * nn * DD + (size_t)n0 * DD, DD, 8, As, Bs, acc);
    int tid = threadIdx.x, lane = tid & 63, w = tid >> 6;
    int rowoff = (w >> 1) * 64, coloff = (w & 1) * 64;
    int r4 = (lane >> 4) * 4, cc = lane & 15;
    #pragma unroll
    for (int mi = 0; mi < 4; mi++)
        #pragma unroll
        for (int nj = 0; nj < 4; nj++)
            #pragma unroll
            for (int rr = 0; rr < 4; rr++) {
                int m = m0 + rowoff + mi * 16 + r4 + rr;
                int col = n0 + coloff + nj * 16 + cc;
                float cv = fmaxf(acc[mi][nj][rr], 0.0f);
                int b = m >> 8, t = m & 255;
                size_t bhtn = (((size_t)(b * HH + h)) * TT + t) * (size_t)nn + col;
                if (mode == 0) {
                    Cx[bhtn] = f2bf(cv);
                } else {
                    cv *= bf2f(mulx[bhtn]);
                    Cy[((size_t)(b * TT + t)) * NN + (size_t)h * nn + col] = f2bf(cv);
                }
            }
}

// ---------------- scores: sc += scale * xrb @ xrb^T (split-K 16, causal tiles) --------
__global__ __launch_bounds__(256) void scores_bt(const unsigned short* __restrict__ xrb,
                                                 float* __restrict__ sc) {
    int zh = blockIdx.z, kc = blockIdx.y, tile = blockIdx.x;
    int t0 = (tile >= 1) ? 128 : 0;
    int s0 = (tile == 2) ? 128 : 0;
    const unsigned short* Xz = xrb + (size_t)zh * TT * nn + (size_t)kc * 512;
    __shared__ unsigned short As[128][36], Bs[128][36];
    f32x4 acc[4][4] = {};
    bt_mainloop(Xz + (size_t)t0 * nn, nn, Xz + (size_t)s0 * nn, nn, 16, As, Bs, acc);
    const float scale = 0.011048543456039805f;   // 1/sqrt(8192)
    int tid = threadIdx.x, lane = tid & 63, w = tid >> 6;
    int rowoff = (w >> 1) * 64, coloff = (w & 1) * 64;
    int r4 = (lane >> 4) * 4, cc = lane & 15;
    float* scz = sc + (size_t)zh * TT * TT;
    #pragma unroll
    for (int mi = 0; mi < 4; mi++)
        #pragma unroll
        for (int nj = 0; nj < 4; nj++)
            #pragma unroll
            for (int rr = 0; rr < 4; rr++) {
                int t = t0 + rowoff + mi * 16 + r4 + rr;
                int s = s0 + coloff + nj * 16 + cc;
                atomicAdd(&scz[(size_t)t * TT + s], acc[mi][nj][rr] * scale);
            }
}

// ---------------- encoder GEMM: yenc += ybf(512x32768) @ encT^T (split-K 32) ----------
__global__ __launch_bounds__(256) void gemm_enc_bt(const unsigned short* __restrict__ A,
                                                   const unsigned short* __restrict__ Bt,
                                                   float* __restrict__ C) {
    int n0 = blockIdx.x * 128, m0 = blockIdx.y * 128;
    long kbase = (long)blockIdx.z * 1024;
    __shared__ unsigned short As[128][36], Bs[128][36];
    f32x4 acc[4][4] = {};
    bt_mainloop(A + (size_t)m0 * NN + kbase, NN,
                Bt + (size_t)n0 * NN + kbase, NN, 32, As, Bs, acc);
    int tid = threadIdx.x, lane = tid & 63, w = tid >> 6;
    int rowoff = (w >> 1) * 64, coloff = (w & 1) * 64;
    int r4 = (lane >> 4) * 4, cc = lane & 15;
    #pragma unroll
    for (int mi = 0; mi < 4; mi++)
        #pragma unroll
        for (int nj = 0; nj < 4; nj++)
            #pragma unroll
            for (int rr = 0; rr < 4; rr++) {
                int row = m0 + rowoff + mi * 16 + r4 + rr;
                int col = n0 + coloff + nj * 16 + cc;
                atomicAdd(&C[(size_t)row * DD + col], acc[mi][nj][rr]);
            }
}

// ---------------- readout: out = vb @ WroT^T, fp32 out ----------------
__global__ __launch_bounds__(256) void gemm_ro_bt(const unsigned short* __restrict__ A,
                                                  const unsigned short* __restrict__ Wt,
                                                  float* __restrict__ out) {
    int n0 = blockIdx.x * 128, m0 = blockIdx.y * 128;
    __shared__ unsigned short As[128][36], Bs[128][36];
    f32x4 acc[4][4] = {};
    bt_mainloop(A + (size_t)m0 * DD, DD, Wt + (size_t)n0 * DD, DD, 8, As, Bs, acc);
    int tid = threadIdx.x, lane = tid & 63, w = tid >> 6;
    int rowoff = (w >> 1) * 64, coloff = (w & 1) * 64;
    int r4 = (lane >> 4) * 4, cc = lane & 15;
    #pragma unroll
    for (int mi = 0; mi < 4; mi++)
        #pragma unroll
        for (int nj = 0; nj < 4; nj++)
            #pragma unroll
            for (int rr = 0; rr < 4; rr++) {
                int m = m0 + rowoff + mi * 16 + r4 + rr;
                int col = n0 + coloff + nj * 16 + cc;
                out[(size_t)m * VV + col] = acc[mi][nj][rr];
            }
}

// ---------------- causal softmax per (b,h,t) + mean over h -> am (B,T,T) ----------------
__global__ __launch_bounds__(256) void softmax_mean_k(const float* __restrict__ sc,
                                                      float* __restrict__ am) {
    int bt = blockIdx.x;
    int b = bt >> 8, t = bt & 255;
    int s = threadIdx.x;
    float acc = 0.0f;
    for (int h = 0; h < HH; h++) {
        const float* row = sc + (((size_t)(b * HH + h)) * TT + t) * TT;
        float val = (s <= t) ? row[s] : -1e30f;
        float mx = block_max(val);
        float e = (s <= t) ? expf(val - mx) : 0.0f;
        float sum = block_sum(e);
        acc += e / sum;
    }
    am[((size_t)b * TT + t) * TT + s] = acc * 0.25f;
}

// ---------------- fp32 NN GEMM — used only for a = am @ v ----------------
__global__ __launch_bounds__(256) void gemm_nn_k(const float* __restrict__ A,
                                                 const float* __restrict__ B,
                                                 float* __restrict__ C,
                                                 int M, int N, int K,
                                                 long lda, long ldb, long ldc,
                                                 long sAz, long sBz, long sCz) {
    int batch = blockIdx.z;
    A += (size_t)batch * sAz;
    B += (size_t)batch * sBz;
    C += (size_t)batch * sCz;
    int m0 = blockIdx.y * 64, n0 = blockIdx.x * 64;
    __shared__ float As[16][68];
    __shared__ float Bs[16][64];
    int tid = threadIdx.x;
    int tx = tid & 15, ty = tid >> 4;
    int ar = tid >> 2, ac = (tid & 3) * 4;
    int br = tid >> 4, bc = (tid & 15) * 4;
    float acc[4][4] = {};
    for (int k0 = 0; k0 < K; k0 += 16) {
        float4 av = *(const float4*)(A + (size_t)(m0 + ar) * lda + k0 + ac);
        float4 bv = *(const float4*)(B + (size_t)(k0 + br) * ldb + n0 + bc);
        As[ac + 0][ar] = av.x; As[ac + 1][ar] = av.y;
        As[ac + 2][ar] = av.z; As[ac + 3][ar] = av.w;
        *(float4*)&Bs[br][bc] = bv;
        __syncthreads();
        #pragma unroll
        for (int k = 0; k < 16; k++) {
            float4 a4 = *(const float4*)&As[k][ty * 4];
            float4 b4 = *(const float4*)&Bs[k][tx * 4];
            float aa[4] = {a4.x, a4.y, a4.z, a4.w};
            float bb[4] = {b4.x, b4.y, b4.z, b4.w};
            #pragma unroll
            for (int i = 0; i < 4; i++)
                #pragma unroll
                for (int j = 0; j < 4; j++)
                    acc[i][j] = fmaf(aa[i], bb[j], acc[i][j]);
        }
        __syncthreads();
    }
    #pragma unroll
    for (int i = 0; i < 4; i++) {
        int m = m0 + ty * 4 + i;
        #pragma unroll
        for (int j = 0; j < 4; j++) {
            int col = n0 + tx * 4 + j;
            C[(size_t)m * ldc + col] = acc[i][j];
        }
    }
}

// ---------------- launch ----------------
extern "C" void kernel_launch(void* const* d_in, const int* in_sizes, int n_in,
                              void* d_out, int out_size, void* d_ws, size_t ws_size,
                              hipStream_t stream) {
    const int*   idx  = (const int*)d_in[0];
    const float* wte  = (const float*)d_in[1];
    const float* enc  = (const float*)d_in[2];
    const float* Wx   = (const float*)d_in[3];
    const float* Wy   = (const float*)d_in[4];
    const float* Wro  = (const float*)d_in[5];
    float* out = (float*)d_out;

    // float region (1,048,576 floats = 4 MB)
    float* ws   = (float*)d_ws;
    float* v    = ws;                  // 131072
    float* sc   = v    + 131072;       // 524288
    float* am   = sc   + 524288;       // 131072
    float* a    = am   + 131072;       // 131072
    float* yenc = a    + 131072;       // 131072
    // short region (58,982,400 shorts ≈ 112.5 MB; total ≈ 116.5 MB < proven 132.5 MB)
    unsigned short* sbase = (unsigned short*)(yenc + 131072);
    unsigned short* vb   = sbase;                 // 131072
    unsigned short* lAb  = vb   + 131072;         // 131072
    unsigned short* xb   = lAb  + 131072;         // 16777216 (B,H,T,n); WroT aliases at end
    unsigned short* xrb  = xb   + 16777216;       // 16777216 (B,H,T,n); ybf aliases
    unsigned short* WxT  = xrb  + 16777216;       // 8388608  [h][8192][256]
    unsigned short* WyT  = WxT  + 8388608;        // 8388608
    unsigned short* encT = WyT  + 8388608;        // 8388608  [256][32768]
    unsigned short* ybf  = xrb;                   // alias: xrb dead after scores
    unsigned short* WroT = xb;                    // alias: xb dead after last y-GEMM

    // pre-pass: weight transpose+convert (once per launch, amortized over 6 layers)
    tconv_k<<<dim3(nn / 64, DD / 64, HH), 256, 0, stream>>>(Wx, WxT, DD, nn,
        (long)DD * nn, (long)nn * DD);
    tconv_k<<<dim3(DD / 64, NN / 64, 1), 256, 0, stream>>>(enc, encT, NN, DD, 0L, 0L);
    tconv_k<<<dim3(nn / 64, DD / 64, HH), 256, 0, stream>>>(Wy, WyT, DD, nn,
        (long)DD * nn, (long)nn * DD);

    // v = ln(wte[idx]) (+ bf16)
    embed_ln_k<<<BB * TT, 256, 0, stream>>>(idx, wte, v, vb);

    for (int l = 0; l < L_LAYERS; l++) {
        // xb = bf16(relu(vb @ WxT[h]))
        gemm_head_bt<<<dim3(nn / 128, (BB * TT) / 128, HH), 256, 0, stream>>>(
            vb, WxT, xb, nullptr, nullptr, 0);

        // xrb = rope(xb)
        rope_b_k<<<(BB * HH * TT * nn / 8) / 256, 256, 0, stream>>>(xb, xrb);

        // sc = scale * xrb @ xrb^T (split-K 16, causal tiles)
        hipMemsetAsync(sc, 0, (size_t)524288 * sizeof(float), stream);
        scores_bt<<<dim3(3, 16, BB * HH), 256, 0, stream>>>(xrb, sc);

        // softmax (causal) + mean over heads
        softmax_mean_k<<<BB * TT, 256, 0, stream>>>(sc, am);

        // a = am @ v (per b), fp32
        gemm_nn_k<<<dim3(DD / 64, TT / 64, BB), 256, 0, stream>>>(
            am, v, a, TT, DD, TT,
            (long)TT, (long)DD, (long)DD,
            (long)TT * TT, (long)TT * DD, (long)TT * DD);

        // lAb = bf16(ln(a))
        ln_rows_k<<<BB * TT, 256, 0, stream>>>(a, lAb);

        // ybf = bf16(relu(lAb @ WyT[h]) * xb)   (ybf aliases xrb)
        gemm_head_bt<<<dim3(nn / 128, (BB * TT) / 128, HH), 256, 0, stream>>>(
            lAb, WyT, nullptr, xb, ybf, 1);

        // yenc = ybf @ enc (split-K 32)
        hipMemsetAsync(yenc, 0, (size_t)131072 * sizeof(float), stream);
        gemm_enc_bt<<<dim3(2, 4, 32), 256, 0, stream>>>(ybf, encT, yenc);

        // v = ln(v + ln(yenc)) (+ bf16)
        add_ln_ln_k<<<BB * TT, 256, 0, stream>>>(v, yenc, vb);
    }

    // WroT = transpose+bf16(Wro) into xb region (xb dead now)
    tconv_k<<<dim3(VV / 64, DD / 64, 1), 256, 0, stream>>>(Wro, WroT, DD, VV, 0L, 0L);

    // out = vb @ WroT^T (fp32 out)
    gemm_ro_bt<<<dim3(VV / 128, (BB * TT) / 128, 1), 256, 0, stream>>>(vb, WroT, out);
}